// Round 4
// baseline (195.935 us; speedup 1.0000x reference)
//
#include <hip/hip_runtime.h>
#include <hip/hip_cooperative_groups.h>
#include <math.h>

#define N 4096

namespace cg = cooperative_groups;

// r3 post-mortem: atomicMax tail on 16KB = same-line RMW serialization -> k_C
// 49.6us. Reverted. Real finding: ~70us of the pipeline is dispatch-boundary
// overhead + exposed latency across 5 tiny dependent kernels (per-kernel
// VALUBusy ~8%, occ ~11%, HBM ~4%). This round: ONE cooperative kernel,
// 256 blocks x 1024 threads (1 block/CU guaranteed: 128-VGPR cap via
// __launch_bounds__(1024,4), 68KB LDS), 4x grid.sync() replacing 4 kernel
// boundaries. All phase math bitwise-identical to the r2-verified kernels.

// Padded f64 cs[] indexing: kills the 32-way bank conflict of stride-64B
// f64 LDS access (pad 1 f64 every 16).
#define CSIDX(t) ((t) + ((t) >> 4))

union SharedU {
    struct { float4 sp4[N / 4]; float4 st4[N / 4]; } pa;            // 32 KB
    struct { float sy[N]; int part[16][65]; } pb;                   // 20.2 KB
    struct { double cs[4360]; float mT[4][16][68]; float iT[4][16][68];
             double wsum[8]; } pc;                                  // ~68.1 KB
    struct { float part[16][65]; } pd;
    struct { float rl[N]; double red[16]; } pe;
};

__global__ __launch_bounds__(1024, 4)
void k_fused(const float* __restrict__ preds, const float* __restrict__ target,
             float* __restrict__ y, float* __restrict__ s, int* __restrict__ perm,
             float* __restrict__ P, float* __restrict__ r, float* __restrict__ out) {
    cg::grid_group grid = cg::this_grid();
    __shared__ SharedU sh;
    int tid = threadIdx.x;
    int b = blockIdx.x;
    int lane = tid & 63, wid = tid >> 6;

    // ---------------- Phase A: softmax matvec + ascending rank -> y ----------
    // 16 waves; wave w owns row i0 = 16b + w. Row max of logits is 0
    // (diagonal term), so single-pass exp == subtract-max softmax exactly.
    {
        sh.pa.sp4[tid] = ((const float4*)preds)[tid];
        sh.pa.st4[tid] = ((const float4*)target)[tid];
        __syncthreads();
        const float* sp = (const float*)sh.pa.sp4;
        int i0 = b * 16 + wid;
        float xv = sp[i0];
        float Z = 0.f, Nm = 0.f;
        int cnt = 0;
        #pragma unroll 4
        for (int m = 0; m < 16; m++) {
            int q = lane + 64 * m;      // float4 index; conflict-free b128
            float4 p4 = sh.pa.sp4[q];
            float4 t4 = sh.pa.st4[q];
            int j = q * 4;
            float d0 = xv - p4.x, d1 = xv - p4.y, d2 = xv - p4.z, d3 = xv - p4.w;
            float e0 = __expf(-100.0f * d0 * d0);
            float e1 = __expf(-100.0f * d1 * d1);
            float e2 = __expf(-100.0f * d2 * d2);
            float e3 = __expf(-100.0f * d3 * d3);
            Z += (e0 + e1) + (e2 + e3);
            Nm += e0 * t4.x + e1 * t4.y + e2 * t4.z + e3 * t4.w;
            cnt += (p4.x < xv) || (p4.x == xv && (j + 0) < i0);
            cnt += (p4.y < xv) || (p4.y == xv && (j + 1) < i0);
            cnt += (p4.z < xv) || (p4.z == xv && (j + 2) < i0);
            cnt += (p4.w < xv) || (p4.w == xv && (j + 3) < i0);
        }
        #pragma unroll
        for (int d = 32; d; d >>= 1) {
            Z += __shfl_down(Z, d);
            Nm += __shfl_down(Nm, d);
            cnt += __shfl_down(cnt, d);
        }
        if (lane == 0) y[cnt] = Nm / Z;
    }
    grid.sync();

    // ---------------- Phase B: descending stable rank; s[r]=y*100, perm -----
    {
        ((float4*)sh.pb.sy)[tid] = ((const float4*)y)[tid];
        __syncthreads();
        int eloc = tid & 15;
        int slice = tid >> 4;           // 0..63
        int i = b * 16 + eloc;
        float v = sh.pb.sy[i];
        int cnt = 0;
        const float4* sy4 = (const float4*)sh.pb.sy;
        #pragma unroll
        for (int it = 0; it < 16; it++) {
            int q = slice * 16 + ((it + slice) & 15);
            float4 a = sy4[q];
            int j = q * 4;
            cnt += (a.x > v) || (a.x == v && (j + 0) < i);
            cnt += (a.y > v) || (a.y == v && (j + 1) < i);
            cnt += (a.z > v) || (a.z == v && (j + 2) < i);
            cnt += (a.w > v) || (a.w == v && (j + 3) < i);
        }
        sh.pb.part[eloc][slice] = cnt;
        __syncthreads();
        if (tid < 16) {
            int rr = 0;
            #pragma unroll
            for (int q = 0; q < 64; q++) rr += sh.pb.part[tid][q];
            int i2 = b * 16 + tid;
            s[rr] = sh.pb.sy[i2] * 100.0f;
            perm[rr] = i2;
        }
    }
    grid.sync();

    // ---------------- Phase C: f64 cumsum + isotonic min-max -> P[b][*] -----
    {
        // Cumsum: waves 0-7 only, 8 elems/thread — bitwise-identical to r2
        // (same serial order, same 64-lane shfl scan, same 8-entry wsum).
        double tot = 0.0, wv = 0.0;
        double loc8[8];
        if (tid < 512) {
            const float4* s4 = (const float4*)s;
            #pragma unroll
            for (int q = 0; q < 2; q++) {
                float4 a = s4[tid * 2 + q];
                int t0 = tid * 8 + q * 4;
                tot += (double)(N - (t0 + 0)) - (double)a.x; loc8[q * 4 + 0] = tot;
                tot += (double)(N - (t0 + 1)) - (double)a.y; loc8[q * 4 + 1] = tot;
                tot += (double)(N - (t0 + 2)) - (double)a.z; loc8[q * 4 + 2] = tot;
                tot += (double)(N - (t0 + 3)) - (double)a.w; loc8[q * 4 + 3] = tot;
            }
            wv = tot;
            #pragma unroll
            for (int d = 1; d < 64; d <<= 1) {
                double o = __shfl_up(wv, d);
                if (lane >= d) wv += o;
            }
            if (lane == 63) sh.pc.wsum[wid] = wv;
        }
        __syncthreads();
        if (tid < 512) {
            double base = 0.0;
            #pragma unroll
            for (int q = 0; q < 8; q++) if (q < wid) base += sh.pc.wsum[q];
            double excl = base + (wv - tot);
            if (tid == 0) sh.pc.cs[CSIDX(0)] = 0.0;
            #pragma unroll
            for (int e = 0; e < 8; e++)
                sh.pc.cs[CSIDX(tid * 8 + 1 + e)] = loc8[e] + excl;
        }
        __syncthreads();

        // Cell compute: all 1024 threads, 4 columns each (kbase..kbase+3).
        int kbase = tid * 4;
        int j0 = b * 16;
        double kloc[4];
        #pragma unroll
        for (int e = 0; e < 4; e++) kloc[e] = sh.pc.cs[CSIDX(kbase + 1 + e)];
        float vloc[4];
        #pragma unroll
        for (int e = 0; e < 4; e++) vloc[e] = -INFINITY;
        float ls[4][4];
        bool live = (tid >= 4 * b);     // cols 4tid.. >= 16b exactly (4 | 16)
        int ce = tid & 15, ct = tid >> 4;
        for (int grp = 0; grp < 4; grp++) {
            if (live) {
                #pragma unroll
                for (int rq = 0; rq < 4; rq++) {
                    int j = j0 + grp * 4 + rq;
                    double csj = sh.pc.cs[CSIDX(j)];   // wave-uniform broadcast
                    float run = INFINITY;
                    #pragma unroll
                    for (int e = 3; e >= 0; e--) {
                        int k = kbase + e;
                        float f = INFINITY;
                        if (k >= j) f = (float)(kloc[e] - csj) * __builtin_amdgcn_rcpf((float)(k - j + 1));
                        run = fminf(f, run);
                        ls[rq][e] = run;
                    }
                    sh.pc.mT[rq][ce][ct] = run;
                }
            } else {
                #pragma unroll
                for (int rq = 0; rq < 4; rq++) sh.pc.mT[rq][ce][ct] = INFINITY;
            }
            __syncthreads();
            // Waves 0-3: suffix-min scan of rq=wid over 1024 chunk minima.
            // Lane l owns chunks 16l..16l+15 via mT[wid][e][l] (lane-consecutive
            // reads -> conflict-free).
            if (wid < 4) {
                float sfx[16];
                {
                    float runm = INFINITY;
                    #pragma unroll
                    for (int e = 15; e >= 0; e--) {
                        runm = fminf(sh.pc.mT[wid][e][lane], runm);
                        sfx[e] = runm;
                    }
                }
                float t = sfx[0];
                #pragma unroll
                for (int d = 1; d < 64; d <<= 1) {
                    float o = __shfl_down(t, d);
                    if (lane + d < 64) t = fminf(t, o);
                }
                float after = __shfl_down(t, 1);
                if (lane == 63) after = INFINITY;
                #pragma unroll
                for (int e = 0; e < 16; e++)
                    sh.pc.iT[wid][e][lane] = fminf(sfx[e], after);
                if (lane == 63) sh.pc.iT[wid][0][64] = INFINITY; // chunk-1024 sentinel
            }
            __syncthreads();
            if (live) {
                int nc = tid + 1;
                #pragma unroll
                for (int rq = 0; rq < 4; rq++) {
                    int j = j0 + grp * 4 + rq;
                    float aft = sh.pc.iT[rq][nc & 15][nc >> 4];
                    #pragma unroll
                    for (int e = 0; e < 4; e++) {
                        int i = kbase + e;
                        float sv = fminf(ls[rq][e], aft);
                        if (i >= j) vloc[e] = fmaxf(vloc[e], sv);
                    }
                }
            }
            __syncthreads();
        }
        if (live)
            ((float4*)(P + (size_t)b * N))[tid] =
                make_float4(vloc[0], vloc[1], vloc[2], vloc[3]);
    }
    grid.sync();

    // ---------------- Phase D: T[i] = max_{bb<=b} P[bb][i]; scatter r -------
    {
        int col = tid & 15;
        int slice = tid >> 4;           // 0..63
        int i = b * 16 + col;
        float m = -INFINITY;
        #pragma unroll
        for (int q = 0; q < 4; q++) {
            int bb = slice * 4 + q;
            if (bb <= b) m = fmaxf(m, P[(size_t)bb * N + i]);
        }
        sh.pd.part[col][slice] = m;
        __syncthreads();
        if (tid < 16) {
            float T = -INFINITY;
            #pragma unroll
            for (int q = 0; q < 64; q++) T = fmaxf(T, sh.pd.part[tid][q]);
            int i2 = b * 16 + tid;
            r[perm[i2]] = s[i2] + T;
        }
    }
    grid.sync();

    // ---------------- Phase E: diff-sum of r (block 0 only) -----------------
    if (b == 0) {
        float4 x = ((const float4*)r)[tid];
        float extra = (tid < 1023) ? r[tid * 4 + 4] : 0.0f;
        double acc = 0.0;
        acc += fabs((double)x.y - (double)x.x);
        acc += fabs((double)x.z - (double)x.y);
        acc += fabs((double)x.w - (double)x.z);
        if (tid < 1023) acc += fabs((double)extra - (double)x.w);
        #pragma unroll
        for (int dd = 32; dd; dd >>= 1) acc += __shfl_down(acc, dd);
        if ((tid & 63) == 0) sh.pe.red[tid >> 6] = acc;
        __syncthreads();
        if (tid == 0) {
            double ds = 0.0;
            #pragma unroll
            for (int q = 0; q < 16; q++) ds += sh.pe.red[q];
            double xi = 1.0 - 3.0 * ds / ((double)N * (double)N - 1.0);
            out[0] = (float)(-1.0 * xi);  // loss = -WEIGHT * xi
            out[1] = (float)xi;
        }
    }
}

extern "C" void kernel_launch(void* const* d_in, const int* in_sizes, int n_in,
                              void* d_out, int out_size, void* d_ws, size_t ws_size,
                              hipStream_t stream) {
    const float* preds  = (const float*)d_in[0];
    const float* target = (const float*)d_in[1];
    float* out = (float*)d_out;

    char* ws = (char*)d_ws;
    float* y    = (float*)(ws);            // 16 KB
    float* s    = (float*)(ws + 16384);    // 16 KB
    int*   perm = (int*)(ws + 32768);      // 16 KB
    float* r    = (float*)(ws + 49152);    // 16 KB
    float* P    = (float*)(ws + 81920);    // 4 MB

    void* kargs[] = {(void*)&preds, (void*)&target, (void*)&y, (void*)&s,
                     (void*)&perm, (void*)&P, (void*)&r, (void*)&out};
    hipLaunchCooperativeKernel((const void*)k_fused, dim3(256), dim3(1024),
                               kargs, 0, stream);
}

// Round 5
// 126.056 us; speedup vs baseline: 1.5543x; 1.5543x over previous
//
#include <hip/hip_runtime.h>
#include <math.h>

#define N 4096

// Cost model (r3/r4 measured): inter-dispatch gap ~13us (L2 wb/inv + launch),
// grid.sync ~27us (worse). So: minimize dispatch count with kernel-boundary
// barriers only. 3 dispatches: A | B | C+hierarchical-last-block(D+E).
// Last-block pattern: plain stores -> __threadfence -> atomicAdd counter;
// the 16th arriver of each 16-block group reduces the group's P rows to P2
// (16 parallel reducers); the 16th group-finisher computes T from P2 and runs
// the finish phase. No spins; forward progress only. All reused phase code is
// bitwise-identical to the r2/r3/r4-verified kernels; new reductions are
// exact-max reorderings with the same bb<=blk guards.

// Padded f64 cs[] indexing: kills the 32-way bank conflict of stride-64B
// f64 LDS access (pad 1 f64 every 16).
#define CSIDX(t) ((t) + ((t) >> 4))

// K_A: fused ascending-rank + softmax matvec -> y, single pass.
// 512 blocks x 512 threads: 8 waves/block, wave w owns row i0 = 8b + w.
// Row max of logits is 0 (diagonal), so single-pass exp == subtract-max.
__global__ __launch_bounds__(512, 4)
void k_A(const float* __restrict__ preds, const float* __restrict__ target,
         float* __restrict__ y) {
    __shared__ __align__(16) float4 sp4[N / 4];
    __shared__ __align__(16) float4 st4[N / 4];
    int tid = threadIdx.x;
    int b = blockIdx.x;
    int lane = tid & 63, wid = tid >> 6;
    const float4* gp = (const float4*)preds;
    const float4* gt = (const float4*)target;
    sp4[tid] = gp[tid];
    sp4[tid + 512] = gp[tid + 512];
    st4[tid] = gt[tid];
    st4[tid + 512] = gt[tid + 512];
    __syncthreads();
    const float* sp = (const float*)sp4;
    int i0 = b * 8 + wid;
    float xv = sp[i0];
    float Z = 0.f, Nm = 0.f;
    int cnt = 0;
    #pragma unroll 4
    for (int m = 0; m < 16; m++) {
        int q = lane + 64 * m;          // float4 index; conflict-free b128
        float4 p4 = sp4[q];
        float4 t4 = st4[q];
        int j = q * 4;
        float d0 = xv - p4.x, d1 = xv - p4.y, d2 = xv - p4.z, d3 = xv - p4.w;
        float e0 = __expf(-100.0f * d0 * d0);
        float e1 = __expf(-100.0f * d1 * d1);
        float e2 = __expf(-100.0f * d2 * d2);
        float e3 = __expf(-100.0f * d3 * d3);
        Z += (e0 + e1) + (e2 + e3);
        Nm += e0 * t4.x + e1 * t4.y + e2 * t4.z + e3 * t4.w;
        cnt += (p4.x < xv) || (p4.x == xv && (j + 0) < i0);
        cnt += (p4.y < xv) || (p4.y == xv && (j + 1) < i0);
        cnt += (p4.z < xv) || (p4.z == xv && (j + 2) < i0);
        cnt += (p4.w < xv) || (p4.w == xv && (j + 3) < i0);
    }
    #pragma unroll
    for (int d = 32; d; d >>= 1) {
        Z += __shfl_down(Z, d);
        Nm += __shfl_down(Nm, d);
        cnt += __shfl_down(cnt, d);
    }
    if (lane == 0) y[cnt] = Nm / Z;
}

// K_B: descending stable rank of y; s[r] = y*100, perm[r] = i.
// Block 0 also zeroes the K3 arrival counters (workspace is poisoned each
// iteration); the dispatch boundary publishes them before K3 starts.
__global__ __launch_bounds__(1024, 4)
void k_B(const float* __restrict__ y, float* __restrict__ s_out,
         int* __restrict__ perm_out, int* __restrict__ cnt) {
    __shared__ __align__(16) float sy[N];
    __shared__ int part[16][65];
    int tid = threadIdx.x;
    int b = blockIdx.x;
    ((float4*)sy)[tid] = ((const float4*)y)[tid];
    if (b == 0 && tid < 32) cnt[tid] = 0;
    __syncthreads();
    int eloc = tid & 15;
    int slice = tid >> 4;               // 0..63
    int i = b * 16 + eloc;
    float v = sy[i];
    int c = 0;
    const float4* sy4 = (const float4*)sy;
    #pragma unroll
    for (int it = 0; it < 16; it++) {
        int q = slice * 16 + ((it + slice) & 15);
        float4 a = sy4[q];
        int j = q * 4;
        c += (a.x > v) || (a.x == v && (j + 0) < i);
        c += (a.y > v) || (a.y == v && (j + 1) < i);
        c += (a.z > v) || (a.z == v && (j + 2) < i);
        c += (a.w > v) || (a.w == v && (j + 3) < i);
    }
    part[eloc][slice] = c;
    __syncthreads();
    if (tid < 16) {
        int r = 0;
        #pragma unroll
        for (int q = 0; q < 64; q++) r += part[tid][q];
        int i2 = b * 16 + tid;
        s_out[r] = sy[i2] * 100.0f;
        perm_out[r] = i2;
    }
}

union SharedU {
    struct { double cs[4360]; float mT[4][16][68]; float iT[4][16][68];
             double wsum[8]; } pc;                                  // ~68.1 KB
    struct { float rl[N]; double red[16]; } pe;                     // 16.2 KB
};

// K_C: f64 cumsum + isotonic min-max -> P[b][*] (r4-verified phase C), then
// hierarchical last-block max-reduction (D) and finish (E) in the same launch.
__global__ __launch_bounds__(1024, 4)
void k_C(const float* __restrict__ s, const int* __restrict__ perm,
         float* __restrict__ P, float* __restrict__ P2, int* __restrict__ cnt,
         float* __restrict__ out) {
    __shared__ SharedU sh;
    __shared__ int role;
    int tid = threadIdx.x;
    int b = blockIdx.x;
    int lane = tid & 63, wid = tid >> 6;

    // ---------------- Phase C (verified, bitwise == r4) ----------------------
    {
        double tot = 0.0, wv = 0.0;
        double loc8[8];
        if (tid < 512) {
            const float4* s4 = (const float4*)s;
            #pragma unroll
            for (int q = 0; q < 2; q++) {
                float4 a = s4[tid * 2 + q];
                int t0 = tid * 8 + q * 4;
                tot += (double)(N - (t0 + 0)) - (double)a.x; loc8[q * 4 + 0] = tot;
                tot += (double)(N - (t0 + 1)) - (double)a.y; loc8[q * 4 + 1] = tot;
                tot += (double)(N - (t0 + 2)) - (double)a.z; loc8[q * 4 + 2] = tot;
                tot += (double)(N - (t0 + 3)) - (double)a.w; loc8[q * 4 + 3] = tot;
            }
            wv = tot;
            #pragma unroll
            for (int d = 1; d < 64; d <<= 1) {
                double o = __shfl_up(wv, d);
                if (lane >= d) wv += o;
            }
            if (lane == 63) sh.pc.wsum[wid] = wv;
        }
        __syncthreads();
        if (tid < 512) {
            double base = 0.0;
            #pragma unroll
            for (int q = 0; q < 8; q++) if (q < wid) base += sh.pc.wsum[q];
            double excl = base + (wv - tot);
            if (tid == 0) sh.pc.cs[CSIDX(0)] = 0.0;
            #pragma unroll
            for (int e = 0; e < 8; e++)
                sh.pc.cs[CSIDX(tid * 8 + 1 + e)] = loc8[e] + excl;
        }
        __syncthreads();

        int kbase = tid * 4;
        int j0 = b * 16;
        double kloc[4];
        #pragma unroll
        for (int e = 0; e < 4; e++) kloc[e] = sh.pc.cs[CSIDX(kbase + 1 + e)];
        float vloc[4];
        #pragma unroll
        for (int e = 0; e < 4; e++) vloc[e] = -INFINITY;
        float ls[4][4];
        bool live = (tid >= 4 * b);     // cols [4tid,4tid+4) vs j0=16b
        int ce = tid & 15, ct = tid >> 4;
        for (int grp = 0; grp < 4; grp++) {
            if (live) {
                #pragma unroll
                for (int rq = 0; rq < 4; rq++) {
                    int j = j0 + grp * 4 + rq;
                    double csj = sh.pc.cs[CSIDX(j)];
                    float run = INFINITY;
                    #pragma unroll
                    for (int e = 3; e >= 0; e--) {
                        int k = kbase + e;
                        float f = INFINITY;
                        if (k >= j) f = (float)(kloc[e] - csj) * __builtin_amdgcn_rcpf((float)(k - j + 1));
                        run = fminf(f, run);
                        ls[rq][e] = run;
                    }
                    sh.pc.mT[rq][ce][ct] = run;
                }
            } else {
                #pragma unroll
                for (int rq = 0; rq < 4; rq++) sh.pc.mT[rq][ce][ct] = INFINITY;
            }
            __syncthreads();
            if (wid < 4) {
                float sfx[16];
                {
                    float runm = INFINITY;
                    #pragma unroll
                    for (int e = 15; e >= 0; e--) {
                        runm = fminf(sh.pc.mT[wid][e][lane], runm);
                        sfx[e] = runm;
                    }
                }
                float t = sfx[0];
                #pragma unroll
                for (int d = 1; d < 64; d <<= 1) {
                    float o = __shfl_down(t, d);
                    if (lane + d < 64) t = fminf(t, o);
                }
                float after = __shfl_down(t, 1);
                if (lane == 63) after = INFINITY;
                #pragma unroll
                for (int e = 0; e < 16; e++)
                    sh.pc.iT[wid][e][lane] = fminf(sfx[e], after);
                if (lane == 63) sh.pc.iT[wid][0][64] = INFINITY;
            }
            __syncthreads();
            if (live) {
                int nc = tid + 1;
                #pragma unroll
                for (int rq = 0; rq < 4; rq++) {
                    int j = j0 + grp * 4 + rq;
                    float aft = sh.pc.iT[rq][nc & 15][nc >> 4];
                    #pragma unroll
                    for (int e = 0; e < 4; e++) {
                        int i = kbase + e;
                        float sv = fminf(ls[rq][e], aft);
                        if (i >= j) vloc[e] = fmaxf(vloc[e], sv);
                    }
                }
            }
            __syncthreads();
        }
        if (live)
            ((float4*)(P + (size_t)b * N))[tid] =
                make_float4(vloc[0], vloc[1], vloc[2], vloc[3]);
    }

    // ---------------- Group last-block: reduce 16 P rows -> P2[g] ------------
    int g = b >> 4;
    __syncthreads();
    if (tid == 0) {
        __threadfence();                         // release P row
        role = (atomicAdd(&cnt[g], 1) == 15);
    }
    __syncthreads();
    if (!role) return;
    __threadfence();                             // acquire group's P rows
    {
        float4 acc = make_float4(-INFINITY, -INFINITY, -INFINITY, -INFINITY);
        #pragma unroll
        for (int u = 0; u < 16; u++) {
            int bb = g * 16 + u;
            if (tid >= 4 * bb) {                 // cols 4tid.. >= 16bb
                float4 pv = ((const float4*)(P + (size_t)bb * N))[tid];
                acc.x = fmaxf(acc.x, pv.x);
                acc.y = fmaxf(acc.y, pv.y);
                acc.z = fmaxf(acc.z, pv.z);
                acc.w = fmaxf(acc.w, pv.w);
            }
        }
        ((float4*)(P2 + (size_t)g * N))[tid] = acc;
    }
    __syncthreads();
    if (tid == 0) {
        __threadfence();                         // release P2 row
        role = (atomicAdd(&cnt[16], 1) == 15);
    }
    __syncthreads();
    if (!role) return;
    __threadfence();                             // acquire all P2 rows

    // ---------------- Final block: T from P2, scatter r, diff-sum ------------
    {
        float4 T4 = make_float4(-INFINITY, -INFINITY, -INFINITY, -INFINITY);
        #pragma unroll
        for (int gg = 0; gg < 16; gg++) {
            if (tid >= 64 * gg) {                // cols 4tid.. >= 256gg
                float4 pv = ((const float4*)(P2 + (size_t)gg * N))[tid];
                T4.x = fmaxf(T4.x, pv.x);
                T4.y = fmaxf(T4.y, pv.y);
                T4.z = fmaxf(T4.z, pv.z);
                T4.w = fmaxf(T4.w, pv.w);
            }
        }
        float4 sv = ((const float4*)s)[tid];
        int4 pe = ((const int4*)perm)[tid];
        sh.pe.rl[pe.x] = sv.x + T4.x;
        sh.pe.rl[pe.y] = sv.y + T4.y;
        sh.pe.rl[pe.z] = sv.z + T4.z;
        sh.pe.rl[pe.w] = sv.w + T4.w;
        __syncthreads();
        float4 x = ((const float4*)sh.pe.rl)[tid];
        float extra = (tid < 1023) ? sh.pe.rl[tid * 4 + 4] : 0.0f;
        double acc = 0.0;
        acc += fabs((double)x.y - (double)x.x);
        acc += fabs((double)x.z - (double)x.y);
        acc += fabs((double)x.w - (double)x.z);
        if (tid < 1023) acc += fabs((double)extra - (double)x.w);
        #pragma unroll
        for (int dd = 32; dd; dd >>= 1) acc += __shfl_down(acc, dd);
        if ((tid & 63) == 0) sh.pe.red[tid >> 6] = acc;
        __syncthreads();
        if (tid == 0) {
            double ds = 0.0;
            #pragma unroll
            for (int q = 0; q < 16; q++) ds += sh.pe.red[q];
            double xi = 1.0 - 3.0 * ds / ((double)N * (double)N - 1.0);
            out[0] = (float)(-1.0 * xi);  // loss = -WEIGHT * xi
            out[1] = (float)xi;
        }
    }
}

extern "C" void kernel_launch(void* const* d_in, const int* in_sizes, int n_in,
                              void* d_out, int out_size, void* d_ws, size_t ws_size,
                              hipStream_t stream) {
    const float* preds  = (const float*)d_in[0];
    const float* target = (const float*)d_in[1];
    float* out = (float*)d_out;

    char* ws = (char*)d_ws;
    float* y    = (float*)(ws);                  // 16 KB
    float* s    = (float*)(ws + 16384);          // 16 KB
    int*   perm = (int*)(ws + 32768);            // 16 KB
    int*   cnt  = (int*)(ws + 49152);            // 128 B (17 used)
    float* P    = (float*)(ws + 81920);          // 4 MB
    float* P2   = (float*)(ws + 81920 + (size_t)N * 256 * 4);  // 256 KB

    k_A<<<512, 512, 0, stream>>>(preds, target, y);
    k_B<<<256, 1024, 0, stream>>>(y, s, perm, cnt);
    k_C<<<256, 1024, 0, stream>>>(s, perm, P, P2, cnt, out);
}

// Round 6
// 94.757 us; speedup vs baseline: 2.0678x; 1.3303x over previous
//
#include <hip/hip_runtime.h>
#include <math.h>

#define N 4096

// Boundary-cost ladder (measured r2-r5): dispatch gap ~13us, grid.sync ~27us,
// threadfence-tree ~60us — all pay for bulk L2 coherence across the 8
// non-coherent XCD L2s. This round: ONE dispatch, dataflow tags instead of
// barriers. Producers write communicated data with atomicExch (executes at the
// fabric coherence point — the primitive class empirically cross-XCD-correct
// in r3/r5), drain vmcnt, then publish a per-block magic tag. Consumers poll
// tags with atomicAdd(tag,0), then read with PLAIN vectorized loads — fresh by
// construction: those lines are first-touched by any XCD only after the tag,
// and atomics never allocate stale L2 copies. Tags need no init (value-match;
// immune to any repeated-dword poison). DAG: A[all]->B, B[all]->C, C[0..b]->D,
// D[all]->E — acyclic; every block produces before it polls; 256 blocks of 16
// waves / <=128 VGPR / 68KB LDS are co-resident under any packing => no
// deadlock. All phase math verbatim from the r2/r4-verified kernels.

#define CSIDX(t) ((t) + ((t) >> 4))
#define TAG(ph, bb) ((0x7E57A5E1ull << 32) | ((unsigned long long)(ph) << 12) | (unsigned long long)(bb))

__device__ __forceinline__ void put_f32(float* p, float v) {
    atomicExch((unsigned int*)p, __float_as_uint(v));   // coherent-point store
}
__device__ __forceinline__ void put_i32(int* p, int v) {
    atomicExch((unsigned int*)p, (unsigned int)v);
}
__device__ __forceinline__ void drain_vm() {
    asm volatile("s_waitcnt vmcnt(0)" ::: "memory");
}
__device__ __forceinline__ void poll_tag(unsigned long long* p, unsigned long long want) {
    while (atomicAdd(p, 0ull) != want) __builtin_amdgcn_s_sleep(8);
}

union SharedU {
    struct { float4 sp4[N / 4]; float4 st4[N / 4]; } pa;            // 32 KB
    struct { float sy[N]; int part[16][65]; } pb;                   // 20.2 KB
    struct { double cs[4360]; float mT[4][16][68]; float iT[4][16][68];
             double wsum[8]; } pc;                                  // ~68.1 KB
    struct { float part[16][65]; } pd;
    struct { double red[16]; } pe;
};

__global__ __launch_bounds__(1024, 4)
void k_all(const float* __restrict__ preds, const float* __restrict__ target,
           float* __restrict__ y, float* __restrict__ s, int* __restrict__ perm,
           float* __restrict__ r, float* __restrict__ P,
           unsigned long long* __restrict__ tags, float* __restrict__ out) {
    __shared__ SharedU sh;
    unsigned long long* doneA = tags;
    unsigned long long* doneB = tags + 256;
    unsigned long long* doneC = tags + 512;
    unsigned long long* doneD = tags + 768;
    int tid = threadIdx.x;
    int b = blockIdx.x;
    int lane = tid & 63, wid = tid >> 6;

    // ---------------- Phase A: softmax matvec + ascending rank -> y ----------
    // (r4-verified) 16 waves; wave w owns row i0 = 16b + w. Row max of logits
    // is 0 (diagonal), so single-pass exp == subtract-max softmax exactly.
    {
        sh.pa.sp4[tid] = ((const float4*)preds)[tid];
        sh.pa.st4[tid] = ((const float4*)target)[tid];
        __syncthreads();
        const float* sp = (const float*)sh.pa.sp4;
        int i0 = b * 16 + wid;
        float xv = sp[i0];
        float Z = 0.f, Nm = 0.f;
        int cnt = 0;
        #pragma unroll 4
        for (int m = 0; m < 16; m++) {
            int q = lane + 64 * m;      // float4 index; conflict-free b128
            float4 p4 = sh.pa.sp4[q];
            float4 t4 = sh.pa.st4[q];
            int j = q * 4;
            float d0 = xv - p4.x, d1 = xv - p4.y, d2 = xv - p4.z, d3 = xv - p4.w;
            float e0 = __expf(-100.0f * d0 * d0);
            float e1 = __expf(-100.0f * d1 * d1);
            float e2 = __expf(-100.0f * d2 * d2);
            float e3 = __expf(-100.0f * d3 * d3);
            Z += (e0 + e1) + (e2 + e3);
            Nm += e0 * t4.x + e1 * t4.y + e2 * t4.z + e3 * t4.w;
            cnt += (p4.x < xv) || (p4.x == xv && (j + 0) < i0);
            cnt += (p4.y < xv) || (p4.y == xv && (j + 1) < i0);
            cnt += (p4.z < xv) || (p4.z == xv && (j + 2) < i0);
            cnt += (p4.w < xv) || (p4.w == xv && (j + 3) < i0);
        }
        #pragma unroll
        for (int d = 32; d; d >>= 1) {
            Z += __shfl_down(Z, d);
            Nm += __shfl_down(Nm, d);
            cnt += __shfl_down(cnt, d);
        }
        if (lane == 0) put_f32(&y[cnt], Nm / Z);
    }
    drain_vm();
    __syncthreads();
    if (tid == 0) atomicExch(&doneA[b], TAG(0, b));

    // ---------------- Phase B: descending stable rank; s[r]=y*100, perm -----
    if (tid < 256) poll_tag(&doneA[tid], TAG(0, tid));
    asm volatile("" ::: "memory");
    __syncthreads();
    {
        ((float4*)sh.pb.sy)[tid] = ((const float4*)y)[tid];   // plain: fresh
        __syncthreads();
        int eloc = tid & 15;
        int slice = tid >> 4;           // 0..63
        int i = b * 16 + eloc;
        float v = sh.pb.sy[i];
        int c = 0;
        const float4* sy4 = (const float4*)sh.pb.sy;
        #pragma unroll
        for (int it = 0; it < 16; it++) {
            int q = slice * 16 + ((it + slice) & 15);
            float4 a = sy4[q];
            int j = q * 4;
            c += (a.x > v) || (a.x == v && (j + 0) < i);
            c += (a.y > v) || (a.y == v && (j + 1) < i);
            c += (a.z > v) || (a.z == v && (j + 2) < i);
            c += (a.w > v) || (a.w == v && (j + 3) < i);
        }
        sh.pb.part[eloc][slice] = c;
        __syncthreads();
        if (tid < 16) {
            int rr = 0;
            #pragma unroll
            for (int q = 0; q < 64; q++) rr += sh.pb.part[tid][q];
            int i2 = b * 16 + tid;
            put_f32(&s[rr], sh.pb.sy[i2] * 100.0f);
            put_i32(&perm[rr], i2);
        }
    }
    drain_vm();
    __syncthreads();
    if (tid == 0) atomicExch(&doneB[b], TAG(1, b));

    // ---------------- Phase C: f64 cumsum + isotonic min-max -> P[b][*] -----
    if (tid < 256) poll_tag(&doneB[tid], TAG(1, tid));
    asm volatile("" ::: "memory");
    __syncthreads();
    {
        double tot = 0.0, wv = 0.0;
        double loc8[8];
        if (tid < 512) {
            const float4* s4 = (const float4*)s;              // plain: fresh
            #pragma unroll
            for (int q = 0; q < 2; q++) {
                float4 a = s4[tid * 2 + q];
                int t0 = tid * 8 + q * 4;
                tot += (double)(N - (t0 + 0)) - (double)a.x; loc8[q * 4 + 0] = tot;
                tot += (double)(N - (t0 + 1)) - (double)a.y; loc8[q * 4 + 1] = tot;
                tot += (double)(N - (t0 + 2)) - (double)a.z; loc8[q * 4 + 2] = tot;
                tot += (double)(N - (t0 + 3)) - (double)a.w; loc8[q * 4 + 3] = tot;
            }
            wv = tot;
            #pragma unroll
            for (int d = 1; d < 64; d <<= 1) {
                double o = __shfl_up(wv, d);
                if (lane >= d) wv += o;
            }
            if (lane == 63) sh.pc.wsum[wid] = wv;
        }
        __syncthreads();
        if (tid < 512) {
            double base = 0.0;
            #pragma unroll
            for (int q = 0; q < 8; q++) if (q < wid) base += sh.pc.wsum[q];
            double excl = base + (wv - tot);
            if (tid == 0) sh.pc.cs[CSIDX(0)] = 0.0;
            #pragma unroll
            for (int e = 0; e < 8; e++)
                sh.pc.cs[CSIDX(tid * 8 + 1 + e)] = loc8[e] + excl;
        }
        __syncthreads();

        int kbase = tid * 4;
        int j0 = b * 16;
        double kloc[4];
        #pragma unroll
        for (int e = 0; e < 4; e++) kloc[e] = sh.pc.cs[CSIDX(kbase + 1 + e)];
        float vloc[4];
        #pragma unroll
        for (int e = 0; e < 4; e++) vloc[e] = -INFINITY;
        float ls[4][4];
        bool live = (tid >= 4 * b);     // cols [4tid,4tid+4) vs j0=16b
        int ce = tid & 15, ct = tid >> 4;
        for (int grp = 0; grp < 4; grp++) {
            if (live) {
                #pragma unroll
                for (int rq = 0; rq < 4; rq++) {
                    int j = j0 + grp * 4 + rq;
                    double csj = sh.pc.cs[CSIDX(j)];
                    float run = INFINITY;
                    #pragma unroll
                    for (int e = 3; e >= 0; e--) {
                        int k = kbase + e;
                        float f = INFINITY;
                        if (k >= j) f = (float)(kloc[e] - csj) * __builtin_amdgcn_rcpf((float)(k - j + 1));
                        run = fminf(f, run);
                        ls[rq][e] = run;
                    }
                    sh.pc.mT[rq][ce][ct] = run;
                }
            } else {
                #pragma unroll
                for (int rq = 0; rq < 4; rq++) sh.pc.mT[rq][ce][ct] = INFINITY;
            }
            __syncthreads();
            if (wid < 4) {
                float sfx[16];
                {
                    float runm = INFINITY;
                    #pragma unroll
                    for (int e = 15; e >= 0; e--) {
                        runm = fminf(sh.pc.mT[wid][e][lane], runm);
                        sfx[e] = runm;
                    }
                }
                float t = sfx[0];
                #pragma unroll
                for (int d = 1; d < 64; d <<= 1) {
                    float o = __shfl_down(t, d);
                    if (lane + d < 64) t = fminf(t, o);
                }
                float after = __shfl_down(t, 1);
                if (lane == 63) after = INFINITY;
                #pragma unroll
                for (int e = 0; e < 16; e++)
                    sh.pc.iT[wid][e][lane] = fminf(sfx[e], after);
                if (lane == 63) sh.pc.iT[wid][0][64] = INFINITY;
            }
            __syncthreads();
            if (live) {
                int nc = tid + 1;
                #pragma unroll
                for (int rq = 0; rq < 4; rq++) {
                    int j = j0 + grp * 4 + rq;
                    float aft = sh.pc.iT[rq][nc & 15][nc >> 4];
                    #pragma unroll
                    for (int e = 0; e < 4; e++) {
                        int i = kbase + e;
                        float sv = fminf(ls[rq][e], aft);
                        if (i >= j) vloc[e] = fmaxf(vloc[e], sv);
                    }
                }
            }
            __syncthreads();
        }
        if (live) {
            float* Pp = P + (size_t)b * N + kbase;
            #pragma unroll
            for (int e = 0; e < 4; e++) put_f32(Pp + e, vloc[e]);
        }
    }
    drain_vm();
    __syncthreads();
    if (tid == 0) atomicExch(&doneC[b], TAG(2, b));

    // ---------------- Phase D: T[i] = max_{bb<=b} P[bb][i]; scatter r -------
    if (tid <= b) poll_tag(&doneC[tid], TAG(2, tid));
    asm volatile("" ::: "memory");
    __syncthreads();
    {
        int col = tid & 15;
        int slice = tid >> 4;           // 0..63
        int i = b * 16 + col;
        float m = -INFINITY;
        #pragma unroll
        for (int q = 0; q < 4; q++) {
            int bb = slice * 4 + q;
            if (bb <= b) m = fmaxf(m, P[(size_t)bb * N + i]);   // plain: fresh
        }
        sh.pd.part[col][slice] = m;
        __syncthreads();
        if (tid < 16) {
            float T = -INFINITY;
            #pragma unroll
            for (int q = 0; q < 64; q++) T = fmaxf(T, sh.pd.part[tid][q]);
            int i2 = b * 16 + tid;
            put_f32(&r[perm[i2]], s[i2] + T);
        }
    }
    drain_vm();
    __syncthreads();
    if (tid == 0) atomicExch(&doneD[b], TAG(3, b));

    // ---------------- Phase E: diff-sum of r (block 0 only) -----------------
    if (b == 0) {
        if (tid < 256) poll_tag(&doneD[tid], TAG(3, tid));
        asm volatile("" ::: "memory");
        __syncthreads();
        float4 x = ((const float4*)r)[tid];                     // plain: fresh
        float extra = (tid < 1023) ? r[tid * 4 + 4] : 0.0f;
        double acc = 0.0;
        acc += fabs((double)x.y - (double)x.x);
        acc += fabs((double)x.z - (double)x.y);
        acc += fabs((double)x.w - (double)x.z);
        if (tid < 1023) acc += fabs((double)extra - (double)x.w);
        #pragma unroll
        for (int dd = 32; dd; dd >>= 1) acc += __shfl_down(acc, dd);
        if ((tid & 63) == 0) sh.pe.red[tid >> 6] = acc;
        __syncthreads();
        if (tid == 0) {
            double ds = 0.0;
            #pragma unroll
            for (int q = 0; q < 16; q++) ds += sh.pe.red[q];
            double xi = 1.0 - 3.0 * ds / ((double)N * (double)N - 1.0);
            out[0] = (float)(-1.0 * xi);  // loss = -WEIGHT * xi
            out[1] = (float)xi;
        }
    }
}

extern "C" void kernel_launch(void* const* d_in, const int* in_sizes, int n_in,
                              void* d_out, int out_size, void* d_ws, size_t ws_size,
                              hipStream_t stream) {
    const float* preds  = (const float*)d_in[0];
    const float* target = (const float*)d_in[1];
    float* out = (float*)d_out;

    char* ws = (char*)d_ws;
    float* y    = (float*)(ws);                        // 16 KB
    float* s    = (float*)(ws + 16384);                // 16 KB
    int*   perm = (int*)(ws + 32768);                  // 16 KB
    float* r    = (float*)(ws + 49152);                // 16 KB
    unsigned long long* tags = (unsigned long long*)(ws + 65536);  // 8 KB
    float* P    = (float*)(ws + 81920);                // 4 MB

    k_all<<<256, 1024, 0, stream>>>(preds, target, y, s, perm, r, P, tags, out);
}

// Round 7
// 93.451 us; speedup vs baseline: 2.0967x; 1.0140x over previous
//
#include <hip/hip_runtime.h>
#include <math.h>

#define N 4096

// One-dispatch dataflow pipeline (r6-verified skeleton), round 7: replace the
// RMW-heavy publication/polling primitives with agent-scope relaxed store/load.
// r6 measured: 44us kernel, VALUBusy 27.9% (=12.3us real work, matching phase
// arithmetic) -> 32us of stall from (a) atomicExch data publication (fabric RMW
// + returned payload on the vmcnt drain), (b) atomicAdd(p,0) poll storms (65K
// concurrent RMW streams at the coherence point), (c) s_sleep(8) quantization.
// Fix: data via __hip_atomic_store(RELAXED, AGENT) (write-through, no return),
// polls via __hip_atomic_load(RELAXED, AGENT) (no RMW) with a bounded fallback
// to the r3/r5/r6-proven atomicAdd every 256 spins (livelock insurance), tags
// still atomicExch. Freshness: lines are first-touched by any reader only
// after the producer's tag (kernel-boundary wb/inv clears all L2s before us;
// within the kernel every read of communicated data is tag-gated), so plain
// vectorized consumer loads remain legal. Ordering: vmcnt drain + syncthreads
// before each tag, exactly as r6. All phase math verbatim from r2/r4/r6.

#define CSIDX(t) ((t) + ((t) >> 4))
#define TAG(ph, bb) ((0x7E57A5E1ull << 32) | ((unsigned long long)(ph) << 12) | (unsigned long long)(bb))

__device__ __forceinline__ void put_f32(float* p, float v) {
    __hip_atomic_store(p, v, __ATOMIC_RELAXED, __HIP_MEMORY_SCOPE_AGENT);
}
__device__ __forceinline__ void put_i32(int* p, int v) {
    __hip_atomic_store(p, v, __ATOMIC_RELAXED, __HIP_MEMORY_SCOPE_AGENT);
}
__device__ __forceinline__ void drain_vm() {
    asm volatile("s_waitcnt vmcnt(0)" ::: "memory");
}
__device__ __forceinline__ void poll_tag(unsigned long long* p, unsigned long long want) {
    int it = 0;
    while (__hip_atomic_load(p, __ATOMIC_RELAXED, __HIP_MEMORY_SCOPE_AGENT) != want) {
        __builtin_amdgcn_s_sleep(2);
        if ((++it & 255) == 0) {
            if (atomicAdd(p, 0ull) == want) break;   // proven-coherent fallback
        }
    }
}

union SharedU {
    struct { float4 sp4[N / 4]; float4 st4[N / 4]; } pa;            // 32 KB
    struct { float sy[N]; int part[16][65]; } pb;                   // 20.2 KB
    struct { double cs[4360]; float mT[4][16][68]; float iT[4][16][68];
             double wsum[8]; } pc;                                  // ~68.1 KB
    struct { float part[16][65]; } pd;
    struct { double red[16]; } pe;
};

__global__ __launch_bounds__(1024, 4)
void k_all(const float* __restrict__ preds, const float* __restrict__ target,
           float* __restrict__ y, float* __restrict__ s, int* __restrict__ perm,
           float* __restrict__ r, float* __restrict__ P,
           unsigned long long* __restrict__ tags, float* __restrict__ out) {
    __shared__ SharedU sh;
    unsigned long long* doneA = tags;
    unsigned long long* doneB = tags + 256;
    unsigned long long* doneC = tags + 512;
    unsigned long long* doneD = tags + 768;
    int tid = threadIdx.x;
    int b = blockIdx.x;
    int lane = tid & 63, wid = tid >> 6;

    // ---------------- Phase A: softmax matvec + ascending rank -> y ----------
    // 16 waves; wave w owns row i0 = 16b + w. Row max of logits is 0
    // (diagonal term), so single-pass exp == subtract-max softmax exactly.
    {
        sh.pa.sp4[tid] = ((const float4*)preds)[tid];
        sh.pa.st4[tid] = ((const float4*)target)[tid];
        __syncthreads();
        const float* sp = (const float*)sh.pa.sp4;
        int i0 = b * 16 + wid;
        float xv = sp[i0];
        float Z = 0.f, Nm = 0.f;
        int cnt = 0;
        #pragma unroll 4
        for (int m = 0; m < 16; m++) {
            int q = lane + 64 * m;      // float4 index; conflict-free b128
            float4 p4 = sh.pa.sp4[q];
            float4 t4 = sh.pa.st4[q];
            int j = q * 4;
            float d0 = xv - p4.x, d1 = xv - p4.y, d2 = xv - p4.z, d3 = xv - p4.w;
            float e0 = __expf(-100.0f * d0 * d0);
            float e1 = __expf(-100.0f * d1 * d1);
            float e2 = __expf(-100.0f * d2 * d2);
            float e3 = __expf(-100.0f * d3 * d3);
            Z += (e0 + e1) + (e2 + e3);
            Nm += e0 * t4.x + e1 * t4.y + e2 * t4.z + e3 * t4.w;
            cnt += (p4.x < xv) || (p4.x == xv && (j + 0) < i0);
            cnt += (p4.y < xv) || (p4.y == xv && (j + 1) < i0);
            cnt += (p4.z < xv) || (p4.z == xv && (j + 2) < i0);
            cnt += (p4.w < xv) || (p4.w == xv && (j + 3) < i0);
        }
        #pragma unroll
        for (int d = 32; d; d >>= 1) {
            Z += __shfl_down(Z, d);
            Nm += __shfl_down(Nm, d);
            cnt += __shfl_down(cnt, d);
        }
        if (lane == 0) put_f32(&y[cnt], Nm / Z);
    }
    drain_vm();
    __syncthreads();
    if (tid == 0) atomicExch(&doneA[b], TAG(0, b));

    // ---------------- Phase B: descending stable rank; s[r]=y*100, perm -----
    if (tid < 256) poll_tag(&doneA[tid], TAG(0, tid));
    asm volatile("" ::: "memory");
    __syncthreads();
    {
        ((float4*)sh.pb.sy)[tid] = ((const float4*)y)[tid];   // plain: fresh
        __syncthreads();
        int eloc = tid & 15;
        int slice = tid >> 4;           // 0..63
        int i = b * 16 + eloc;
        float v = sh.pb.sy[i];
        int c = 0;
        const float4* sy4 = (const float4*)sh.pb.sy;
        #pragma unroll
        for (int it = 0; it < 16; it++) {
            int q = slice * 16 + ((it + slice) & 15);
            float4 a = sy4[q];
            int j = q * 4;
            c += (a.x > v) || (a.x == v && (j + 0) < i);
            c += (a.y > v) || (a.y == v && (j + 1) < i);
            c += (a.z > v) || (a.z == v && (j + 2) < i);
            c += (a.w > v) || (a.w == v && (j + 3) < i);
        }
        sh.pb.part[eloc][slice] = c;
        __syncthreads();
        if (tid < 16) {
            int rr = 0;
            #pragma unroll
            for (int q = 0; q < 64; q++) rr += sh.pb.part[tid][q];
            int i2 = b * 16 + tid;
            put_f32(&s[rr], sh.pb.sy[i2] * 100.0f);
            put_i32(&perm[rr], i2);
        }
    }
    drain_vm();
    __syncthreads();
    if (tid == 0) atomicExch(&doneB[b], TAG(1, b));

    // ---------------- Phase C: f64 cumsum + isotonic min-max -> P[b][*] -----
    if (tid < 256) poll_tag(&doneB[tid], TAG(1, tid));
    asm volatile("" ::: "memory");
    __syncthreads();
    {
        double tot = 0.0, wv = 0.0;
        double loc8[8];
        if (tid < 512) {
            const float4* s4 = (const float4*)s;              // plain: fresh
            #pragma unroll
            for (int q = 0; q < 2; q++) {
                float4 a = s4[tid * 2 + q];
                int t0 = tid * 8 + q * 4;
                tot += (double)(N - (t0 + 0)) - (double)a.x; loc8[q * 4 + 0] = tot;
                tot += (double)(N - (t0 + 1)) - (double)a.y; loc8[q * 4 + 1] = tot;
                tot += (double)(N - (t0 + 2)) - (double)a.z; loc8[q * 4 + 2] = tot;
                tot += (double)(N - (t0 + 3)) - (double)a.w; loc8[q * 4 + 3] = tot;
            }
            wv = tot;
            #pragma unroll
            for (int d = 1; d < 64; d <<= 1) {
                double o = __shfl_up(wv, d);
                if (lane >= d) wv += o;
            }
            if (lane == 63) sh.pc.wsum[wid] = wv;
        }
        __syncthreads();
        if (tid < 512) {
            double base = 0.0;
            #pragma unroll
            for (int q = 0; q < 8; q++) if (q < wid) base += sh.pc.wsum[q];
            double excl = base + (wv - tot);
            if (tid == 0) sh.pc.cs[CSIDX(0)] = 0.0;
            #pragma unroll
            for (int e = 0; e < 8; e++)
                sh.pc.cs[CSIDX(tid * 8 + 1 + e)] = loc8[e] + excl;
        }
        __syncthreads();

        int kbase = tid * 4;
        int j0 = b * 16;
        double kloc[4];
        #pragma unroll
        for (int e = 0; e < 4; e++) kloc[e] = sh.pc.cs[CSIDX(kbase + 1 + e)];
        float vloc[4];
        #pragma unroll
        for (int e = 0; e < 4; e++) vloc[e] = -INFINITY;
        float ls[4][4];
        bool live = (tid >= 4 * b);     // cols [4tid,4tid+4) vs j0=16b
        int ce = tid & 15, ct = tid >> 4;
        for (int grp = 0; grp < 4; grp++) {
            if (live) {
                #pragma unroll
                for (int rq = 0; rq < 4; rq++) {
                    int j = j0 + grp * 4 + rq;
                    double csj = sh.pc.cs[CSIDX(j)];
                    float run = INFINITY;
                    #pragma unroll
                    for (int e = 3; e >= 0; e--) {
                        int k = kbase + e;
                        float f = INFINITY;
                        if (k >= j) f = (float)(kloc[e] - csj) * __builtin_amdgcn_rcpf((float)(k - j + 1));
                        run = fminf(f, run);
                        ls[rq][e] = run;
                    }
                    sh.pc.mT[rq][ce][ct] = run;
                }
            } else {
                #pragma unroll
                for (int rq = 0; rq < 4; rq++) sh.pc.mT[rq][ce][ct] = INFINITY;
            }
            __syncthreads();
            if (wid < 4) {
                float sfx[16];
                {
                    float runm = INFINITY;
                    #pragma unroll
                    for (int e = 15; e >= 0; e--) {
                        runm = fminf(sh.pc.mT[wid][e][lane], runm);
                        sfx[e] = runm;
                    }
                }
                float t = sfx[0];
                #pragma unroll
                for (int d = 1; d < 64; d <<= 1) {
                    float o = __shfl_down(t, d);
                    if (lane + d < 64) t = fminf(t, o);
                }
                float after = __shfl_down(t, 1);
                if (lane == 63) after = INFINITY;
                #pragma unroll
                for (int e = 0; e < 16; e++)
                    sh.pc.iT[wid][e][lane] = fminf(sfx[e], after);
                if (lane == 63) sh.pc.iT[wid][0][64] = INFINITY;
            }
            __syncthreads();
            if (live) {
                int nc = tid + 1;
                #pragma unroll
                for (int rq = 0; rq < 4; rq++) {
                    int j = j0 + grp * 4 + rq;
                    float aft = sh.pc.iT[rq][nc & 15][nc >> 4];
                    #pragma unroll
                    for (int e = 0; e < 4; e++) {
                        int i = kbase + e;
                        float sv = fminf(ls[rq][e], aft);
                        if (i >= j) vloc[e] = fmaxf(vloc[e], sv);
                    }
                }
            }
            __syncthreads();
        }
        if (live) {
            float* Pp = P + (size_t)b * N + kbase;
            #pragma unroll
            for (int e = 0; e < 4; e++) put_f32(Pp + e, vloc[e]);
        }
    }
    drain_vm();
    __syncthreads();
    if (tid == 0) atomicExch(&doneC[b], TAG(2, b));

    // ---------------- Phase D: T[i] = max_{bb<=b} P[bb][i]; scatter r -------
    if (tid <= b) poll_tag(&doneC[tid], TAG(2, tid));
    asm volatile("" ::: "memory");
    __syncthreads();
    {
        int col = tid & 15;
        int slice = tid >> 4;           // 0..63
        int i = b * 16 + col;
        float m = -INFINITY;
        #pragma unroll
        for (int q = 0; q < 4; q++) {
            int bb = slice * 4 + q;
            if (bb <= b) m = fmaxf(m, P[(size_t)bb * N + i]);   // plain: fresh
        }
        sh.pd.part[col][slice] = m;
        __syncthreads();
        if (tid < 16) {
            float T = -INFINITY;
            #pragma unroll
            for (int q = 0; q < 64; q++) T = fmaxf(T, sh.pd.part[tid][q]);
            int i2 = b * 16 + tid;
            put_f32(&r[perm[i2]], s[i2] + T);
        }
    }
    drain_vm();
    __syncthreads();
    if (tid == 0) atomicExch(&doneD[b], TAG(3, b));

    // ---------------- Phase E: diff-sum of r (block 0 only) -----------------
    if (b == 0) {
        if (tid < 256) poll_tag(&doneD[tid], TAG(3, tid));
        asm volatile("" ::: "memory");
        __syncthreads();
        float4 x = ((const float4*)r)[tid];                     // plain: fresh
        float extra = (tid < 1023) ? r[tid * 4 + 4] : 0.0f;
        double acc = 0.0;
        acc += fabs((double)x.y - (double)x.x);
        acc += fabs((double)x.z - (double)x.y);
        acc += fabs((double)x.w - (double)x.z);
        if (tid < 1023) acc += fabs((double)extra - (double)x.w);
        #pragma unroll
        for (int dd = 32; dd; dd >>= 1) acc += __shfl_down(acc, dd);
        if ((tid & 63) == 0) sh.pe.red[tid >> 6] = acc;
        __syncthreads();
        if (tid == 0) {
            double ds = 0.0;
            #pragma unroll
            for (int q = 0; q < 16; q++) ds += sh.pe.red[q];
            double xi = 1.0 - 3.0 * ds / ((double)N * (double)N - 1.0);
            out[0] = (float)(-1.0 * xi);  // loss = -WEIGHT * xi
            out[1] = (float)xi;
        }
    }
}

extern "C" void kernel_launch(void* const* d_in, const int* in_sizes, int n_in,
                              void* d_out, int out_size, void* d_ws, size_t ws_size,
                              hipStream_t stream) {
    const float* preds  = (const float*)d_in[0];
    const float* target = (const float*)d_in[1];
    float* out = (float*)d_out;

    char* ws = (char*)d_ws;
    float* y    = (float*)(ws);                        // 16 KB
    float* s    = (float*)(ws + 16384);                // 16 KB
    int*   perm = (int*)(ws + 32768);                  // 16 KB
    float* r    = (float*)(ws + 49152);                // 16 KB
    unsigned long long* tags = (unsigned long long*)(ws + 65536);  // 8 KB
    float* P    = (float*)(ws + 81920);                // 4 MB

    k_all<<<256, 1024, 0, stream>>>(preds, target, y, s, perm, r, P, tags, out);
}

// Round 8
// 91.775 us; speedup vs baseline: 2.1349x; 1.0183x over previous
//
#include <hip/hip_runtime.h>
#include <math.h>

#define N 4096

// One-dispatch dataflow pipeline (r6/r7-verified skeleton), round 8.
// r7 post-mortem: primitive swap (RMW->relaxed) was null; the smoking gun is
// WRITE_SIZE 8610KB (vs 2320KB with plain float4 stores in r5) — scalar dword
// agent-scope publication of P (~2MB) = 524K individual write-through fabric
// transactions, each with its own ack on the phase-C vmcnt(0) drain. This
// round, ONE variable: publish P with a single global_store_dwordx4 sc0 sc1
// (16B coherent write-through, 4x fewer transactions/acks). Tags, polls,
// ordering, and all phase math are byte-identical to r7 (passed, absmax 0).

#define CSIDX(t) ((t) + ((t) >> 4))
#define TAG(ph, bb) ((0x7E57A5E1ull << 32) | ((unsigned long long)(ph) << 12) | (unsigned long long)(bb))

typedef float f32x4 __attribute__((ext_vector_type(4)));

__device__ __forceinline__ void put_f32(float* p, float v) {
    __hip_atomic_store(p, v, __ATOMIC_RELAXED, __HIP_MEMORY_SCOPE_AGENT);
}
__device__ __forceinline__ void put_i32(int* p, int v) {
    __hip_atomic_store(p, v, __ATOMIC_RELAXED, __HIP_MEMORY_SCOPE_AGENT);
}
// 16B agent/system-coherent write-through store: one fabric transaction.
__device__ __forceinline__ void put_f32x4(float* p, f32x4 v) {
    asm volatile("global_store_dwordx4 %0, %1, off sc0 sc1"
                 :: "v"(p), "v"(v) : "memory");
}
__device__ __forceinline__ void drain_vm() {
    asm volatile("s_waitcnt vmcnt(0)" ::: "memory");
}
__device__ __forceinline__ void poll_tag(unsigned long long* p, unsigned long long want) {
    int it = 0;
    while (__hip_atomic_load(p, __ATOMIC_RELAXED, __HIP_MEMORY_SCOPE_AGENT) != want) {
        __builtin_amdgcn_s_sleep(2);
        if ((++it & 255) == 0) {
            if (atomicAdd(p, 0ull) == want) break;   // proven-coherent fallback
        }
    }
}

union SharedU {
    struct { float4 sp4[N / 4]; float4 st4[N / 4]; } pa;            // 32 KB
    struct { float sy[N]; int part[16][65]; } pb;                   // 20.2 KB
    struct { double cs[4360]; float mT[4][16][68]; float iT[4][16][68];
             double wsum[8]; } pc;                                  // ~68.1 KB
    struct { float part[16][65]; } pd;
    struct { double red[16]; } pe;
};

__global__ __launch_bounds__(1024, 4)
void k_all(const float* __restrict__ preds, const float* __restrict__ target,
           float* __restrict__ y, float* __restrict__ s, int* __restrict__ perm,
           float* __restrict__ r, float* __restrict__ P,
           unsigned long long* __restrict__ tags, float* __restrict__ out) {
    __shared__ SharedU sh;
    unsigned long long* doneA = tags;
    unsigned long long* doneB = tags + 256;
    unsigned long long* doneC = tags + 512;
    unsigned long long* doneD = tags + 768;
    int tid = threadIdx.x;
    int b = blockIdx.x;
    int lane = tid & 63, wid = tid >> 6;

    // ---------------- Phase A: softmax matvec + ascending rank -> y ----------
    // 16 waves; wave w owns row i0 = 16b + w. Row max of logits is 0
    // (diagonal term), so single-pass exp == subtract-max softmax exactly.
    {
        sh.pa.sp4[tid] = ((const float4*)preds)[tid];
        sh.pa.st4[tid] = ((const float4*)target)[tid];
        __syncthreads();
        const float* sp = (const float*)sh.pa.sp4;
        int i0 = b * 16 + wid;
        float xv = sp[i0];
        float Z = 0.f, Nm = 0.f;
        int cnt = 0;
        #pragma unroll 4
        for (int m = 0; m < 16; m++) {
            int q = lane + 64 * m;      // float4 index; conflict-free b128
            float4 p4 = sh.pa.sp4[q];
            float4 t4 = sh.pa.st4[q];
            int j = q * 4;
            float d0 = xv - p4.x, d1 = xv - p4.y, d2 = xv - p4.z, d3 = xv - p4.w;
            float e0 = __expf(-100.0f * d0 * d0);
            float e1 = __expf(-100.0f * d1 * d1);
            float e2 = __expf(-100.0f * d2 * d2);
            float e3 = __expf(-100.0f * d3 * d3);
            Z += (e0 + e1) + (e2 + e3);
            Nm += e0 * t4.x + e1 * t4.y + e2 * t4.z + e3 * t4.w;
            cnt += (p4.x < xv) || (p4.x == xv && (j + 0) < i0);
            cnt += (p4.y < xv) || (p4.y == xv && (j + 1) < i0);
            cnt += (p4.z < xv) || (p4.z == xv && (j + 2) < i0);
            cnt += (p4.w < xv) || (p4.w == xv && (j + 3) < i0);
        }
        #pragma unroll
        for (int d = 32; d; d >>= 1) {
            Z += __shfl_down(Z, d);
            Nm += __shfl_down(Nm, d);
            cnt += __shfl_down(cnt, d);
        }
        if (lane == 0) put_f32(&y[cnt], Nm / Z);
    }
    drain_vm();
    __syncthreads();
    if (tid == 0) atomicExch(&doneA[b], TAG(0, b));

    // ---------------- Phase B: descending stable rank; s[r]=y*100, perm -----
    if (tid < 256) poll_tag(&doneA[tid], TAG(0, tid));
    asm volatile("" ::: "memory");
    __syncthreads();
    {
        ((float4*)sh.pb.sy)[tid] = ((const float4*)y)[tid];   // plain: fresh
        __syncthreads();
        int eloc = tid & 15;
        int slice = tid >> 4;           // 0..63
        int i = b * 16 + eloc;
        float v = sh.pb.sy[i];
        int c = 0;
        const float4* sy4 = (const float4*)sh.pb.sy;
        #pragma unroll
        for (int it = 0; it < 16; it++) {
            int q = slice * 16 + ((it + slice) & 15);
            float4 a = sy4[q];
            int j = q * 4;
            c += (a.x > v) || (a.x == v && (j + 0) < i);
            c += (a.y > v) || (a.y == v && (j + 1) < i);
            c += (a.z > v) || (a.z == v && (j + 2) < i);
            c += (a.w > v) || (a.w == v && (j + 3) < i);
        }
        sh.pb.part[eloc][slice] = c;
        __syncthreads();
        if (tid < 16) {
            int rr = 0;
            #pragma unroll
            for (int q = 0; q < 64; q++) rr += sh.pb.part[tid][q];
            int i2 = b * 16 + tid;
            put_f32(&s[rr], sh.pb.sy[i2] * 100.0f);
            put_i32(&perm[rr], i2);
        }
    }
    drain_vm();
    __syncthreads();
    if (tid == 0) atomicExch(&doneB[b], TAG(1, b));

    // ---------------- Phase C: f64 cumsum + isotonic min-max -> P[b][*] -----
    if (tid < 256) poll_tag(&doneB[tid], TAG(1, tid));
    asm volatile("" ::: "memory");
    __syncthreads();
    {
        double tot = 0.0, wv = 0.0;
        double loc8[8];
        if (tid < 512) {
            const float4* s4 = (const float4*)s;              // plain: fresh
            #pragma unroll
            for (int q = 0; q < 2; q++) {
                float4 a = s4[tid * 2 + q];
                int t0 = tid * 8 + q * 4;
                tot += (double)(N - (t0 + 0)) - (double)a.x; loc8[q * 4 + 0] = tot;
                tot += (double)(N - (t0 + 1)) - (double)a.y; loc8[q * 4 + 1] = tot;
                tot += (double)(N - (t0 + 2)) - (double)a.z; loc8[q * 4 + 2] = tot;
                tot += (double)(N - (t0 + 3)) - (double)a.w; loc8[q * 4 + 3] = tot;
            }
            wv = tot;
            #pragma unroll
            for (int d = 1; d < 64; d <<= 1) {
                double o = __shfl_up(wv, d);
                if (lane >= d) wv += o;
            }
            if (lane == 63) sh.pc.wsum[wid] = wv;
        }
        __syncthreads();
        if (tid < 512) {
            double base = 0.0;
            #pragma unroll
            for (int q = 0; q < 8; q++) if (q < wid) base += sh.pc.wsum[q];
            double excl = base + (wv - tot);
            if (tid == 0) sh.pc.cs[CSIDX(0)] = 0.0;
            #pragma unroll
            for (int e = 0; e < 8; e++)
                sh.pc.cs[CSIDX(tid * 8 + 1 + e)] = loc8[e] + excl;
        }
        __syncthreads();

        int kbase = tid * 4;
        int j0 = b * 16;
        double kloc[4];
        #pragma unroll
        for (int e = 0; e < 4; e++) kloc[e] = sh.pc.cs[CSIDX(kbase + 1 + e)];
        float vloc[4];
        #pragma unroll
        for (int e = 0; e < 4; e++) vloc[e] = -INFINITY;
        float ls[4][4];
        bool live = (tid >= 4 * b);     // cols [4tid,4tid+4) vs j0=16b
        int ce = tid & 15, ct = tid >> 4;
        for (int grp = 0; grp < 4; grp++) {
            if (live) {
                #pragma unroll
                for (int rq = 0; rq < 4; rq++) {
                    int j = j0 + grp * 4 + rq;
                    double csj = sh.pc.cs[CSIDX(j)];
                    float run = INFINITY;
                    #pragma unroll
                    for (int e = 3; e >= 0; e--) {
                        int k = kbase + e;
                        float f = INFINITY;
                        if (k >= j) f = (float)(kloc[e] - csj) * __builtin_amdgcn_rcpf((float)(k - j + 1));
                        run = fminf(f, run);
                        ls[rq][e] = run;
                    }
                    sh.pc.mT[rq][ce][ct] = run;
                }
            } else {
                #pragma unroll
                for (int rq = 0; rq < 4; rq++) sh.pc.mT[rq][ce][ct] = INFINITY;
            }
            __syncthreads();
            if (wid < 4) {
                float sfx[16];
                {
                    float runm = INFINITY;
                    #pragma unroll
                    for (int e = 15; e >= 0; e--) {
                        runm = fminf(sh.pc.mT[wid][e][lane], runm);
                        sfx[e] = runm;
                    }
                }
                float t = sfx[0];
                #pragma unroll
                for (int d = 1; d < 64; d <<= 1) {
                    float o = __shfl_down(t, d);
                    if (lane + d < 64) t = fminf(t, o);
                }
                float after = __shfl_down(t, 1);
                if (lane == 63) after = INFINITY;
                #pragma unroll
                for (int e = 0; e < 16; e++)
                    sh.pc.iT[wid][e][lane] = fminf(sfx[e], after);
                if (lane == 63) sh.pc.iT[wid][0][64] = INFINITY;
            }
            __syncthreads();
            if (live) {
                int nc = tid + 1;
                #pragma unroll
                for (int rq = 0; rq < 4; rq++) {
                    int j = j0 + grp * 4 + rq;
                    float aft = sh.pc.iT[rq][nc & 15][nc >> 4];
                    #pragma unroll
                    for (int e = 0; e < 4; e++) {
                        int i = kbase + e;
                        float sv = fminf(ls[rq][e], aft);
                        if (i >= j) vloc[e] = fmaxf(vloc[e], sv);
                    }
                }
            }
            __syncthreads();
        }
        if (live) {
            f32x4 pv = {vloc[0], vloc[1], vloc[2], vloc[3]};
            put_f32x4(P + (size_t)b * N + kbase, pv);   // ONE 16B transaction
        }
    }
    drain_vm();
    __syncthreads();
    if (tid == 0) atomicExch(&doneC[b], TAG(2, b));

    // ---------------- Phase D: T[i] = max_{bb<=b} P[bb][i]; scatter r -------
    if (tid <= b) poll_tag(&doneC[tid], TAG(2, tid));
    asm volatile("" ::: "memory");
    __syncthreads();
    {
        int col = tid & 15;
        int slice = tid >> 4;           // 0..63
        int i = b * 16 + col;
        float m = -INFINITY;
        #pragma unroll
        for (int q = 0; q < 4; q++) {
            int bb = slice * 4 + q;
            if (bb <= b) m = fmaxf(m, P[(size_t)bb * N + i]);   // plain: fresh
        }
        sh.pd.part[col][slice] = m;
        __syncthreads();
        if (tid < 16) {
            float T = -INFINITY;
            #pragma unroll
            for (int q = 0; q < 64; q++) T = fmaxf(T, sh.pd.part[tid][q]);
            int i2 = b * 16 + tid;
            put_f32(&r[perm[i2]], s[i2] + T);
        }
    }
    drain_vm();
    __syncthreads();
    if (tid == 0) atomicExch(&doneD[b], TAG(3, b));

    // ---------------- Phase E: diff-sum of r (block 0 only) -----------------
    if (b == 0) {
        if (tid < 256) poll_tag(&doneD[tid], TAG(3, tid));
        asm volatile("" ::: "memory");
        __syncthreads();
        float4 x = ((const float4*)r)[tid];                     // plain: fresh
        float extra = (tid < 1023) ? r[tid * 4 + 4] : 0.0f;
        double acc = 0.0;
        acc += fabs((double)x.y - (double)x.x);
        acc += fabs((double)x.z - (double)x.y);
        acc += fabs((double)x.w - (double)x.z);
        if (tid < 1023) acc += fabs((double)extra - (double)x.w);
        #pragma unroll
        for (int dd = 32; dd; dd >>= 1) acc += __shfl_down(acc, dd);
        if ((tid & 63) == 0) sh.pe.red[tid >> 6] = acc;
        __syncthreads();
        if (tid == 0) {
            double ds = 0.0;
            #pragma unroll
            for (int q = 0; q < 16; q++) ds += sh.pe.red[q];
            double xi = 1.0 - 3.0 * ds / ((double)N * (double)N - 1.0);
            out[0] = (float)(-1.0 * xi);  // loss = -WEIGHT * xi
            out[1] = (float)xi;
        }
    }
}

extern "C" void kernel_launch(void* const* d_in, const int* in_sizes, int n_in,
                              void* d_out, int out_size, void* d_ws, size_t ws_size,
                              hipStream_t stream) {
    const float* preds  = (const float*)d_in[0];
    const float* target = (const float*)d_in[1];
    float* out = (float*)d_out;

    char* ws = (char*)d_ws;
    float* y    = (float*)(ws);                        // 16 KB
    float* s    = (float*)(ws + 16384);                // 16 KB
    int*   perm = (int*)(ws + 32768);                  // 16 KB
    float* r    = (float*)(ws + 49152);                // 16 KB
    unsigned long long* tags = (unsigned long long*)(ws + 65536);  // 8 KB
    float* P    = (float*)(ws + 81920);                // 4 MB

    k_all<<<256, 1024, 0, stream>>>(preds, target, y, s, perm, r, P, tags, out);
}

// Round 9
// 87.313 us; speedup vs baseline: 2.2441x; 1.0511x over previous
//
#include <hip/hip_runtime.h>
#include <math.h>

#define N 4096

// Envelope model (calibrated r6-r8): dur = ~50.5us fixed harness envelope +
// sum(kernels) + ~3us per in-graph dispatch gap. Single-dispatch tag-sync is
// capped by ~8us/boundary poll+skew cost (and showed a 14.5ms stale-poll
// outlier in r8) -> abandoned. This round: the r2 5-dispatch skeleton (cheap
// boundaries, no spins) with k_C replaced by the r8-verified 1024-thread
// phase-C (4 cols/thread, padded f64 cs[], 2x TLP of the old 512-thread
// version whose ~16us dominated r2's controllable time). All math bitwise-
// identical to previously verified rounds (absmax 0.0 in r1/r2 and r4-r8).

#define CSIDX(t) ((t) + ((t) >> 4))

// K_A: fused ascending-rank + softmax matvec -> y, single pass (r1-verified).
// 256 blocks x 1024 threads; wave w owns row i0 = 16b + w. Row max of logits
// is 0 (diagonal term), so single-pass exp == subtract-max softmax exactly.
__global__ __launch_bounds__(1024, 4)
void k_A(const float* __restrict__ preds, const float* __restrict__ target,
         float* __restrict__ y) {
    __shared__ __align__(16) float4 sp4[N / 4];
    __shared__ __align__(16) float4 st4[N / 4];
    int tid = threadIdx.x;
    int b = blockIdx.x;
    int lane = tid & 63, wid = tid >> 6;
    sp4[tid] = ((const float4*)preds)[tid];
    st4[tid] = ((const float4*)target)[tid];
    __syncthreads();
    const float* sp = (const float*)sp4;
    int i0 = b * 16 + wid;
    float xv = sp[i0];
    float Z = 0.f, Nm = 0.f;
    int cnt = 0;
    #pragma unroll 4
    for (int m = 0; m < 16; m++) {
        int q = lane + 64 * m;          // float4 index; conflict-free b128
        float4 p4 = sp4[q];
        float4 t4 = st4[q];
        int j = q * 4;
        float d0 = xv - p4.x, d1 = xv - p4.y, d2 = xv - p4.z, d3 = xv - p4.w;
        float e0 = __expf(-100.0f * d0 * d0);
        float e1 = __expf(-100.0f * d1 * d1);
        float e2 = __expf(-100.0f * d2 * d2);
        float e3 = __expf(-100.0f * d3 * d3);
        Z += (e0 + e1) + (e2 + e3);
        Nm += e0 * t4.x + e1 * t4.y + e2 * t4.z + e3 * t4.w;
        cnt += (p4.x < xv) || (p4.x == xv && (j + 0) < i0);
        cnt += (p4.y < xv) || (p4.y == xv && (j + 1) < i0);
        cnt += (p4.z < xv) || (p4.z == xv && (j + 2) < i0);
        cnt += (p4.w < xv) || (p4.w == xv && (j + 3) < i0);
    }
    #pragma unroll
    for (int d = 32; d; d >>= 1) {
        Z += __shfl_down(Z, d);
        Nm += __shfl_down(Nm, d);
        cnt += __shfl_down(cnt, d);
    }
    if (lane == 0) y[cnt] = Nm / Z;
}

// K_B: descending stable rank of y; s[r] = y*100, perm[r] = i (r2-verified).
__global__ __launch_bounds__(1024, 4)
void k_B(const float* __restrict__ y, float* __restrict__ s_out,
         int* __restrict__ perm_out) {
    __shared__ __align__(16) float sy[N];
    __shared__ int part[16][65];
    int tid = threadIdx.x;
    int b = blockIdx.x;
    ((float4*)sy)[tid] = ((const float4*)y)[tid];
    __syncthreads();
    int eloc = tid & 15;
    int slice = tid >> 4;               // 0..63
    int i = b * 16 + eloc;
    float v = sy[i];
    int c = 0;
    const float4* sy4 = (const float4*)sy;
    #pragma unroll
    for (int it = 0; it < 16; it++) {
        int q = slice * 16 + ((it + slice) & 15);
        float4 a = sy4[q];
        int j = q * 4;
        c += (a.x > v) || (a.x == v && (j + 0) < i);
        c += (a.y > v) || (a.y == v && (j + 1) < i);
        c += (a.z > v) || (a.z == v && (j + 2) < i);
        c += (a.w > v) || (a.w == v && (j + 3) < i);
    }
    part[eloc][slice] = c;
    __syncthreads();
    if (tid < 16) {
        int r = 0;
        #pragma unroll
        for (int q = 0; q < 64; q++) r += part[tid][q];
        int i2 = b * 16 + tid;
        s_out[r] = sy[i2] * 100.0f;
        perm_out[r] = i2;
    }
}

// K_C: f64 cumsum of z[t]=(N-t)-s[t] + isotonic min-max scan -> P[b][*].
// 1024 threads, 4 columns/thread (the r4/r8-verified formulation: double the
// TLP and half the per-thread serial cell loop of the old 512-thread k_C,
// which measured ~16us and dominated r2). Plain float4 P stores; the dispatch
// boundary provides coherence for k_reduce.
__global__ __launch_bounds__(1024, 4)
void k_C(const float* __restrict__ s, float* __restrict__ P) {
    __shared__ double cs[4360];
    __shared__ float mT[4][16][68];
    __shared__ float iT[4][16][68];
    __shared__ double wsum[8];
    int tid = threadIdx.x;
    int b = blockIdx.x;
    int lane = tid & 63, wid = tid >> 6;

    // Cumsum: waves 0-7, 8 elems/thread — bitwise-identical to r2's order.
    double tot = 0.0, wv = 0.0;
    double loc8[8];
    if (tid < 512) {
        const float4* s4 = (const float4*)s;
        #pragma unroll
        for (int q = 0; q < 2; q++) {
            float4 a = s4[tid * 2 + q];
            int t0 = tid * 8 + q * 4;
            tot += (double)(N - (t0 + 0)) - (double)a.x; loc8[q * 4 + 0] = tot;
            tot += (double)(N - (t0 + 1)) - (double)a.y; loc8[q * 4 + 1] = tot;
            tot += (double)(N - (t0 + 2)) - (double)a.z; loc8[q * 4 + 2] = tot;
            tot += (double)(N - (t0 + 3)) - (double)a.w; loc8[q * 4 + 3] = tot;
        }
        wv = tot;
        #pragma unroll
        for (int d = 1; d < 64; d <<= 1) {
            double o = __shfl_up(wv, d);
            if (lane >= d) wv += o;
        }
        if (lane == 63) wsum[wid] = wv;
    }
    __syncthreads();
    if (tid < 512) {
        double base = 0.0;
        #pragma unroll
        for (int q = 0; q < 8; q++) if (q < wid) base += wsum[q];
        double excl = base + (wv - tot);
        if (tid == 0) cs[CSIDX(0)] = 0.0;
        #pragma unroll
        for (int e = 0; e < 8; e++)
            cs[CSIDX(tid * 8 + 1 + e)] = loc8[e] + excl;
    }
    __syncthreads();

    // Cell compute: all 1024 threads, 4 columns each.
    int kbase = tid * 4;
    int j0 = b * 16;
    double kloc[4];
    #pragma unroll
    for (int e = 0; e < 4; e++) kloc[e] = cs[CSIDX(kbase + 1 + e)];
    float vloc[4];
    #pragma unroll
    for (int e = 0; e < 4; e++) vloc[e] = -INFINITY;
    float ls[4][4];
    bool live = (tid >= 4 * b);         // cols [4tid,4tid+4) vs j0=16b
    int ce = tid & 15, ct = tid >> 4;
    for (int grp = 0; grp < 4; grp++) {
        if (live) {
            #pragma unroll
            for (int rq = 0; rq < 4; rq++) {
                int j = j0 + grp * 4 + rq;
                double csj = cs[CSIDX(j)];          // wave-uniform broadcast
                float run = INFINITY;
                #pragma unroll
                for (int e = 3; e >= 0; e--) {
                    int k = kbase + e;
                    float f = INFINITY;
                    if (k >= j) f = (float)(kloc[e] - csj) * __builtin_amdgcn_rcpf((float)(k - j + 1));
                    run = fminf(f, run);
                    ls[rq][e] = run;
                }
                mT[rq][ce][ct] = run;
            }
        } else {
            #pragma unroll
            for (int rq = 0; rq < 4; rq++) mT[rq][ce][ct] = INFINITY;
        }
        __syncthreads();
        // Waves 0-3: suffix-min scan of rq=wid over 1024 chunk minima.
        // Lane l owns chunks 16l..16l+15 via mT[wid][e][l] (lane-consecutive).
        if (wid < 4) {
            float sfx[16];
            {
                float runm = INFINITY;
                #pragma unroll
                for (int e = 15; e >= 0; e--) {
                    runm = fminf(mT[wid][e][lane], runm);
                    sfx[e] = runm;
                }
            }
            float t = sfx[0];
            #pragma unroll
            for (int d = 1; d < 64; d <<= 1) {
                float o = __shfl_down(t, d);
                if (lane + d < 64) t = fminf(t, o);
            }
            float after = __shfl_down(t, 1);
            if (lane == 63) after = INFINITY;
            #pragma unroll
            for (int e = 0; e < 16; e++)
                iT[wid][e][lane] = fminf(sfx[e], after);
            if (lane == 63) iT[wid][0][64] = INFINITY;  // chunk-1024 sentinel
        }
        __syncthreads();
        if (live) {
            int nc = tid + 1;
            #pragma unroll
            for (int rq = 0; rq < 4; rq++) {
                int j = j0 + grp * 4 + rq;
                float aft = iT[rq][nc & 15][nc >> 4];
                #pragma unroll
                for (int e = 0; e < 4; e++) {
                    int i = kbase + e;
                    float sv = fminf(ls[rq][e], aft);
                    if (i >= j) vloc[e] = fmaxf(vloc[e], sv);
                }
            }
        }
        __syncthreads();
    }
    if (live)
        ((float4*)(P + (size_t)b * N))[tid] =
            make_float4(vloc[0], vloc[1], vloc[2], vloc[3]);
}

// K_reduce: T[i] = max_{bb<=blk} P[bb][i]; r[perm[i]] = s[i] + T[i]
// (r2-verified).
__global__ __launch_bounds__(1024, 4)
void k_reduce(const float* __restrict__ P, const float* __restrict__ s,
              const int* __restrict__ perm, float* __restrict__ r) {
    __shared__ float part[16][65];
    int tid = threadIdx.x;
    int col = tid & 15;
    int slice = tid >> 4;               // 0..63
    int blk = blockIdx.x;
    int i = blk * 16 + col;
    float m = -INFINITY;
    #pragma unroll
    for (int q = 0; q < 4; q++) {
        int bb = slice * 4 + q;
        if (bb <= blk) m = fmaxf(m, P[(size_t)bb * N + i]);
    }
    part[col][slice] = m;
    __syncthreads();
    if (tid < 16) {
        float T = -INFINITY;
        #pragma unroll
        for (int q = 0; q < 64; q++) T = fmaxf(T, part[tid][q]);
        int i2 = blk * 16 + tid;
        r[perm[i2]] = s[i2] + T;
    }
}

// K_finish2: diff-sum over r in original order; emit out (r2-verified).
__global__ __launch_bounds__(1024, 4)
void k_finish2(const float* __restrict__ r, float* __restrict__ out) {
    __shared__ double red[16];
    int tid = threadIdx.x;
    const float4* r4 = (const float4*)r;
    float4 x = r4[tid];
    float extra = (tid < 1023) ? r[tid * 4 + 4] : 0.0f;
    double acc = 0.0;
    acc += fabs((double)x.y - (double)x.x);
    acc += fabs((double)x.z - (double)x.y);
    acc += fabs((double)x.w - (double)x.z);
    if (tid < 1023) acc += fabs((double)extra - (double)x.w);
    #pragma unroll
    for (int dd = 32; dd; dd >>= 1) acc += __shfl_down(acc, dd);
    if ((tid & 63) == 0) red[tid >> 6] = acc;
    __syncthreads();
    if (tid == 0) {
        double ds = 0.0;
        #pragma unroll
        for (int q = 0; q < 16; q++) ds += red[q];
        double xi = 1.0 - 3.0 * ds / ((double)N * (double)N - 1.0);
        out[0] = (float)(-1.0 * xi);  // loss = -WEIGHT * xi
        out[1] = (float)xi;
    }
}

extern "C" void kernel_launch(void* const* d_in, const int* in_sizes, int n_in,
                              void* d_out, int out_size, void* d_ws, size_t ws_size,
                              hipStream_t stream) {
    const float* preds  = (const float*)d_in[0];
    const float* target = (const float*)d_in[1];
    float* out = (float*)d_out;

    char* ws = (char*)d_ws;
    float* y    = (float*)(ws);            // 16 KB
    float* s    = (float*)(ws + 16384);    // 16 KB
    int*   perm = (int*)(ws + 32768);      // 16 KB
    float* r    = (float*)(ws + 49152);    // 16 KB
    float* P    = (float*)(ws + 81920);    // 4 MB

    k_A<<<256, 1024, 0, stream>>>(preds, target, y);
    k_B<<<256, 1024, 0, stream>>>(y, s, perm);
    k_C<<<256, 1024, 0, stream>>>(s, P);
    k_reduce<<<256, 1024, 0, stream>>>(P, s, perm, r);
    k_finish2<<<1, 1024, 0, stream>>>(r, out);
}